// Round 6
// baseline (254.979 us; speedup 1.0000x reference)
//
#include <hip/hip_runtime.h>

#define N_NODES 50000
#define N_EDGES 800000
#define F_IN    512
#define H_DIM   256
#define C_DIM   64
#define MPAD    50048   // 391 * 128

// sort geometry: bucket = row >> 8 (256 rows/bucket), chunk = 16384 edges
#define NB      196
#define NCHUNK  49
#define CHUNK   16384
#define BCAP    6144

// spmm1 slicing: 8 slices x 32 dims; 16 rows/block (4 waves x 4 rows)
#define SLICES  8
#define SW      32
#define RPW     4
#define RPB     16
#define SPB     (N_NODES / RPB)   // 3125 blocks per slice

typedef __bf16 bf16;
typedef __bf16 bf16x2 __attribute__((ext_vector_type(2)));
typedef __bf16 bf16x4 __attribute__((ext_vector_type(4)));
typedef __bf16 bf16x8 __attribute__((ext_vector_type(8)));
typedef float  f32x4  __attribute__((ext_vector_type(4)));
typedef unsigned int u32;
typedef unsigned char u8;

__device__ __forceinline__ void gl_lds16(const void* g, void* l) {
    __builtin_amdgcn_global_load_lds(
        (const __attribute__((address_space(1))) u32*)g,
        (__attribute__((address_space(3))) u32*)l, 16, 0, 0);
}

__device__ __forceinline__ float unpack_val(u32 pk) {
    return __builtin_bit_cast(float, pk << 16);
}

// ---------------- edge sort: two-level counting sort, coalesced writes ----------------

__global__ __launch_bounds__(1024) void histA_k(const int* __restrict__ rows,
                                                u32* __restrict__ G) {
    __shared__ u32 h[16 * NB];
    int tid = threadIdx.x, wid = tid >> 6;
    for (int i = tid; i < 16 * NB; i += 1024) h[i] = 0;
    __syncthreads();
    int base = blockIdx.x * CHUNK;
    int end = base + CHUNK; if (end > N_EDGES) end = N_EDGES;
    for (int e = base + tid; e < end; e += 1024)
        atomicAdd(&h[wid * NB + (rows[e] >> 8)], 1);
    __syncthreads();
    if (tid < NB) {
        u32 s = 0;
#pragma unroll
        for (int w = 0; w < 16; w++) s += h[w * NB + tid];
        G[tid * NCHUNK + blockIdx.x] = s;
    }
}

// scatter: recomputes bucket-base + chunk-prefix locally (no separate scan kernels)
__global__ __launch_bounds__(1024) void scatterB_k(const int* __restrict__ rows,
                                                   const int* __restrict__ cols,
                                                   const float* __restrict__ vals,
                                                   const u32* __restrict__ G,
                                                   u32* __restrict__ epack,
                                                   u8* __restrict__ lrow) {
    __shared__ u32 cur[NB];
    __shared__ u32 wtot[16];
    int tid = threadIdx.x, wid = tid >> 6, lane = tid & 63;
    int c = blockIdx.x;
    u32 tot = 0, pre = 0;
    if (tid < NB) {
        for (int cc = 0; cc < NCHUNK; cc++) {
            u32 v = G[tid * NCHUNK + cc];
            tot += v;
            if (cc < c) pre += v;
        }
    }
    u32 incl = tot;
#pragma unroll
    for (int off = 1; off < 64; off <<= 1) {
        u32 u = __shfl_up(incl, off, 64);
        if (lane >= off) incl += u;
    }
    if (lane == 63) wtot[wid] = incl;
    __syncthreads();
    u32 wpre = 0;
#pragma unroll
    for (int w = 0; w < 16; w++)
        if (w < wid) wpre += wtot[w];
    if (tid < NB) cur[tid] = (wpre + incl - tot) + pre;
    __syncthreads();
    int base = c * CHUNK;
    int end = base + CHUNK; if (end > N_EDGES) end = N_EDGES;
    for (int e = base + tid; e < end; e += 1024) {
        int r = rows[e];
        unsigned short vb = __builtin_bit_cast(unsigned short, (bf16)vals[e]);
        u32 pk = ((u32)cols[e] << 16) | (u32)vb;
        u32 p = atomicAdd(&cur[r >> 8], 1);
        epack[p] = pk;
        lrow[p] = (u8)(r & 255);
    }
}

// in-LDS counting sort within bucket; recomputes its bbase locally
__global__ __launch_bounds__(256) void sortC_k(u32* __restrict__ epack,
                                               const u8* __restrict__ lrow,
                                               const u32* __restrict__ G,
                                               int* __restrict__ starts) {
    __shared__ u32 edat[BCAP];
    __shared__ u32 sdat[BCAP];
    __shared__ u8  erow[BCAP];
    __shared__ u32 h[4 * 256];
    __shared__ u32 cur[256];
    __shared__ u32 wt1[4], wt2[4];
    __shared__ u32 sh_s, sh_n;
    int b = blockIdx.x, tid = threadIdx.x, wid = tid >> 6, lane = tid & 63;

    // recompute bucket bases: scan of per-bucket totals over 256 threads
    u32 btot = 0;
    if (tid < NB)
        for (int cc = 0; cc < NCHUNK; cc++) btot += G[tid * NCHUNK + cc];
    u32 bincl = btot;
#pragma unroll
    for (int off = 1; off < 64; off <<= 1) {
        u32 u = __shfl_up(bincl, off, 64);
        if (lane >= off) bincl += u;
    }
    if (lane == 63) wt1[wid] = bincl;
    __syncthreads();
    u32 bwpre = 0;
#pragma unroll
    for (int w = 0; w < 4; w++)
        if (w < wid) bwpre += wt1[w];
    if (tid == b) { sh_s = bwpre + bincl - btot; sh_n = btot; }
    __syncthreads();
    int s = (int)sh_s;
    int n = (int)sh_n;
    if (n > BCAP) n = BCAP;

    for (int i = tid; i < n; i += 256) { edat[i] = epack[s + i]; erow[i] = lrow[s + i]; }
    for (int i = tid; i < 1024; i += 256) h[i] = 0;
    __syncthreads();
    for (int i = tid; i < n; i += 256) atomicAdd(&h[wid * 256 + erow[i]], 1);
    __syncthreads();
    u32 tot = h[tid] + h[256 + tid] + h[512 + tid] + h[768 + tid];
    u32 incl = tot;
#pragma unroll
    for (int off = 1; off < 64; off <<= 1) {
        u32 u = __shfl_up(incl, off, 64);
        if (lane >= off) incl += u;
    }
    if (lane == 63) wt2[wid] = incl;
    __syncthreads();
    u32 wpre = 0;
#pragma unroll
    for (int w = 0; w < 4; w++)
        if (w < wid) wpre += wt2[w];
    u32 excl = wpre + incl - tot;
    cur[tid] = excl;
    int grow = b * 256 + tid;
    if (grow < N_NODES) starts[grow] = s + (int)excl;
    if (b == 0 && tid == 0) starts[N_NODES] = N_EDGES;
    __syncthreads();
    for (int i = tid; i < n; i += 256) {
        u32 p = atomicAdd(&cur[erow[i]], 1);
        sdat[p] = edat[i];
    }
    __syncthreads();
    for (int i = tid; i < n; i += 256) epack[s + i] = sdat[i];
}

// ---------------- weight prep (merged) ----------------

__global__ __launch_bounds__(256) void tr_w_k(const float* __restrict__ W1,
                                              const float* __restrict__ W2,
                                              bf16* __restrict__ W1t,
                                              bf16* __restrict__ W2t) {
    int i = blockIdx.x * 256 + threadIdx.x;
    if (i < F_IN * H_DIM) {
        int k = i >> 8, n = i & 255;
        W1t[n * F_IN + k] = (bf16)W1[i];
    } else {
        int j = i - F_IN * H_DIM;
        int k = j >> 6, n = j & 63;
        W2t[n * H_DIM + k] = (bf16)W2[j];
    }
}

// ---------------- GEMM1 fused: C[M,256] = bf16(A_f32[M,512]) @ W1t^T + b1 ----------------

__global__ __launch_bounds__(512) void gemm1_k(const float* __restrict__ A,
                                               const bf16* __restrict__ Bt,
                                               const float* __restrict__ bias,
                                               bf16* __restrict__ C) {
    constexpr int BM = 128, BN = 256, BK = 64;
    __shared__ bf16 As[BM * BK];
    __shared__ bf16 Bs[BN * BK];

    int tid = threadIdx.x;
    int wid = tid >> 6, lane = tid & 63;
    int wr = wid >> 2, wc = wid & 3;
    int bm = blockIdx.x;

    f32x4 acc[4][4];
#pragma unroll
    for (int m = 0; m < 4; m++)
#pragma unroll
        for (int n = 0; n < 4; n++) acc[m][n] = (f32x4){0.f, 0.f, 0.f, 0.f};

    for (int kt = 0; kt < F_IN; kt += BK) {
#pragma unroll
        for (int j = 0; j < 4; j++) {
            int ch = j * 512 + tid;
            int row = ch >> 3, kc = ch & 7;
            gl_lds16(Bt + (size_t)row * F_IN + kt + kc * 8,
                     &Bs[(j * 512 + wid * 64) * 8]);
        }
#pragma unroll
        for (int j = 0; j < 2; j++) {
            int ch = j * 512 + tid;
            int row = ch >> 3, kc = ch & 7;
            int ar = bm * BM + row;
            if (ar >= N_NODES) ar = N_NODES - 1;
            const f32x4* src = (const f32x4*)(A + (size_t)ar * F_IN + kt + kc * 8);
            f32x4 u = src[0], v = src[1];
            bf16x8 o;
            o[0] = (bf16)u[0]; o[1] = (bf16)u[1]; o[2] = (bf16)u[2]; o[3] = (bf16)u[3];
            o[4] = (bf16)v[0]; o[5] = (bf16)v[1]; o[6] = (bf16)v[2]; o[7] = (bf16)v[3];
            *(bf16x8*)&As[(size_t)ch * 8] = o;
        }
        __syncthreads();

        bf16x8 afr[2][4], bfr[2][4];
#pragma unroll
        for (int kk = 0; kk < 2; kk++) {
#pragma unroll
            for (int m = 0; m < 4; m++)
                afr[kk][m] = *(const bf16x8*)&As[(wr * 64 + m * 16 + (lane & 15)) * BK +
                                                 kk * 32 + (lane >> 4) * 8];
#pragma unroll
            for (int n = 0; n < 4; n++)
                bfr[kk][n] = *(const bf16x8*)&Bs[(wc * 64 + n * 16 + (lane & 15)) * BK +
                                                 kk * 32 + (lane >> 4) * 8];
        }
#pragma unroll
        for (int kk = 0; kk < 2; kk++)
#pragma unroll
            for (int m = 0; m < 4; m++)
#pragma unroll
                for (int n = 0; n < 4; n++)
                    acc[m][n] = __builtin_amdgcn_mfma_f32_16x16x32_bf16(
                        afr[kk][m], bfr[kk][n], acc[m][n], 0, 0, 0);
        __syncthreads();
    }

#pragma unroll
    for (int m = 0; m < 4; m++) {
        int row0 = bm * BM + wr * 64 + m * 16 + (lane >> 4) * 4;
#pragma unroll
        for (int n = 0; n < 4; n++) {
            int col = wc * 64 + n * 16 + (lane & 15);
            float bz = bias[col];
#pragma unroll
            for (int r = 0; r < 4; r++) {
                int row = row0 + r;
                if (row < N_NODES)
                    C[(size_t)row * H_DIM + col] = (bf16)(acc[m][n][r] + bz);
            }
        }
    }
}

// ---------------- GEMM2: C[M,64] = x16[M,256] @ W2t^T + b2 (bf16 in/out) ----------------

__global__ __launch_bounds__(256) void gemm2_k(const bf16* __restrict__ A,
                                               const bf16* __restrict__ Bt,
                                               const float* __restrict__ bias,
                                               bf16* __restrict__ C) {
    constexpr int BM = 128, BN = 64, BK = 64;
    __shared__ bf16 As[BM * BK];
    __shared__ bf16 Bs[BN * BK];

    int tid = threadIdx.x;
    int wid = tid >> 6, lane = tid & 63;
    int wr = wid >> 1, wc = wid & 1;
    int bm = blockIdx.x;

    f32x4 acc[4][2];
#pragma unroll
    for (int m = 0; m < 4; m++)
#pragma unroll
        for (int n = 0; n < 2; n++) acc[m][n] = (f32x4){0.f, 0.f, 0.f, 0.f};

    for (int kt = 0; kt < H_DIM; kt += BK) {
#pragma unroll
        for (int j = 0; j < 4; j++) {
            int ch = j * 256 + tid;
            int row = ch >> 3, kc = ch & 7;
            gl_lds16(A + (size_t)(bm * BM + row) * H_DIM + kt + kc * 8,
                     &As[(j * 256 + wid * 64) * 8]);
        }
#pragma unroll
        for (int j = 0; j < 2; j++) {
            int ch = j * 256 + tid;
            int row = ch >> 3, kc = ch & 7;
            gl_lds16(Bt + (size_t)row * H_DIM + kt + kc * 8,
                     &Bs[(j * 256 + wid * 64) * 8]);
        }
        __syncthreads();

        bf16x8 afr[2][4], bfr[2][2];
#pragma unroll
        for (int kk = 0; kk < 2; kk++) {
#pragma unroll
            for (int m = 0; m < 4; m++)
                afr[kk][m] = *(const bf16x8*)&As[(wr * 64 + m * 16 + (lane & 15)) * BK +
                                                 kk * 32 + (lane >> 4) * 8];
#pragma unroll
            for (int n = 0; n < 2; n++)
                bfr[kk][n] = *(const bf16x8*)&Bs[(wc * 32 + n * 16 + (lane & 15)) * BK +
                                                 kk * 32 + (lane >> 4) * 8];
        }
#pragma unroll
        for (int kk = 0; kk < 2; kk++)
#pragma unroll
            for (int m = 0; m < 4; m++)
#pragma unroll
                for (int n = 0; n < 2; n++)
                    acc[m][n] = __builtin_amdgcn_mfma_f32_16x16x32_bf16(
                        afr[kk][m], bfr[kk][n], acc[m][n], 0, 0, 0);
        __syncthreads();
    }

#pragma unroll
    for (int m = 0; m < 4; m++) {
        int row0 = bm * BM + wr * 64 + m * 16 + (lane >> 4) * 4;
#pragma unroll
        for (int n = 0; n < 2; n++) {
            int col = wc * 32 + n * 16 + (lane & 15);
            float bz = bias[col];
#pragma unroll
            for (int r = 0; r < 4; r++) {
                int row = row0 + r;
                if (row < N_NODES)
                    C[(size_t)row * C_DIM + col] = (bf16)(acc[m][n][r] + bz);
            }
        }
    }
}

// ---------------- SpMM1 sliced: 8 slices x 32 dims, L2-resident gather table ----------------
// Block = 4 waves x 4 rows, slice-major grid. Per wave-iter: 2 batches of 4 edges;
// 16 lanes per edge load bf16x2 -> one 64B line per edge gather.

__global__ __launch_bounds__(256) void spmm1s_k(const int* __restrict__ starts,
                                                const u32* __restrict__ epack,
                                                const bf16* __restrict__ s1,
                                                bf16* __restrict__ x16) {
    int tid = threadIdx.x, wid = tid >> 6, lane = tid & 63;
    int g = lane >> 4, d2 = lane & 15;
    int bid = blockIdx.x;
    int sl = bid / SPB, rb = bid - sl * SPB;
    int dimoff = sl * SW + d2 * 2;
    const bf16* s1d = s1 + dimoff;
#pragma unroll
    for (int rr = 0; rr < RPW; rr++) {
        int row = rb * RPB + wid * RPW + rr;
        int s = starts[row], e = starts[row + 1];
        float a0 = 0.f, a1 = 0.f;
        for (int p = s; p < e; p += 8) {
            int p0 = p + g, p1 = p + 4 + g;
            u32 k0 = (p0 < e) ? epack[p0] : 0u;
            u32 k1 = (p1 < e) ? epack[p1] : 0u;
            bf16x2 g0 = *(const bf16x2*)(s1d + (size_t)(k0 >> 16) * H_DIM);
            bf16x2 g1 = *(const bf16x2*)(s1d + (size_t)(k1 >> 16) * H_DIM);
            float v0 = unpack_val(k0), v1 = unpack_val(k1);
            a0 += v0 * (float)g0[0] + v1 * (float)g1[0];
            a1 += v0 * (float)g0[1] + v1 * (float)g1[1];
        }
        a0 += __shfl_xor(a0, 16, 64); a0 += __shfl_xor(a0, 32, 64);
        a1 += __shfl_xor(a1, 16, 64); a1 += __shfl_xor(a1, 32, 64);
        if (g == 0) {
            bf16x2 o;
            o[0] = (bf16)fmaxf(a0, 0.f);
            o[1] = (bf16)fmaxf(a1, 0.f);
            *(bf16x2*)(x16 + (size_t)row * H_DIM + dimoff) = o;
        }
    }
}

// ---------------- SpMM2 + log_softmax fused: D=64, lane = class, bf16 gather ----------------

__global__ __launch_bounds__(256) void spmm2_sm_k(const int* __restrict__ starts,
                                                  const u32* __restrict__ epack,
                                                  const bf16* __restrict__ s2,
                                                  float* __restrict__ out) {
    int wid = threadIdx.x >> 6, lane = threadIdx.x & 63;
    int row = blockIdx.x * 4 + wid;
    if (row >= N_NODES) return;
    int s = starts[row], e = starts[row + 1];
    float acc = 0.f;
    int p = s;
    for (; p + 4 <= e; p += 4) {
        u32 k0 = epack[p], k1 = epack[p + 1], k2 = epack[p + 2], k3 = epack[p + 3];
        float g0 = (float)s2[(size_t)(k0 >> 16) * C_DIM + lane];
        float g1 = (float)s2[(size_t)(k1 >> 16) * C_DIM + lane];
        float g2 = (float)s2[(size_t)(k2 >> 16) * C_DIM + lane];
        float g3 = (float)s2[(size_t)(k3 >> 16) * C_DIM + lane];
        acc += unpack_val(k0) * g0 + unpack_val(k1) * g1 +
               unpack_val(k2) * g2 + unpack_val(k3) * g3;
    }
    for (; p < e; ++p) {
        u32 k = epack[p];
        acc += unpack_val(k) * (float)s2[(size_t)(k >> 16) * C_DIM + lane];
    }
    float mx = acc;
#pragma unroll
    for (int off = 32; off >= 1; off >>= 1) mx = fmaxf(mx, __shfl_xor(mx, off, 64));
    float ex = expf(acc - mx);
    float se = ex;
#pragma unroll
    for (int off = 32; off >= 1; off >>= 1) se += __shfl_xor(se, off, 64);
    out[(size_t)row * C_DIM + lane] = (acc - mx) - logf(se);
}

// ---------------- launch ----------------

extern "C" void kernel_launch(void* const* d_in, const int* in_sizes, int n_in,
                              void* d_out, int out_size, void* d_ws, size_t ws_size,
                              hipStream_t stream) {
    const float* nf   = (const float*)d_in[0];
    const int*   rows = (const int*)d_in[1];
    const int*   cols = (const int*)d_in[2];
    const float* vals = (const float*)d_in[3];
    const float* W1   = (const float*)d_in[4];
    const float* b1   = (const float*)d_in[5];
    const float* W2   = (const float*)d_in[6];
    const float* b2   = (const float*)d_in[7];
    float* out = (float*)d_out;

    char* w = (char*)d_ws;
    auto alloc = [&](size_t b) { void* p = (void*)w; w += (b + 255) & ~(size_t)255; return p; };

    bf16* x16  = (bf16*)alloc((size_t)MPAD * H_DIM * 2);
    bf16* sup1 = (bf16*)alloc((size_t)N_NODES * H_DIM * 2);
    bf16* sup2 = sup1;   // aliases sup1 (dead by then)
    bf16* W1t = (bf16*)alloc((size_t)H_DIM * F_IN * 2);
    bf16* W2t = (bf16*)alloc((size_t)C_DIM * H_DIM * 2);
    int* starts = (int*)alloc((size_t)(N_NODES + 1) * 4);
    u32* G      = (u32*)alloc((size_t)NB * NCHUNK * 4);
    u32* epack  = (u32*)alloc((size_t)N_EDGES * 4);
    u8*  lrow   = (u8*)alloc((size_t)N_EDGES);

    // edge sort (3 kernels: hist, scatter+local-scan, bucket-sort)
    histA_k<<<NCHUNK, 1024, 0, stream>>>(rows, G);
    scatterB_k<<<NCHUNK, 1024, 0, stream>>>(rows, cols, vals, G, epack, lrow);
    sortC_k<<<NB, 256, 0, stream>>>(epack, lrow, G, starts);

    // weight prep
    tr_w_k<<<(F_IN * H_DIM + H_DIM * C_DIM) / 256, 256, 0, stream>>>(W1, W2, W1t, W2t);

    // layer 1
    gemm1_k<<<MPAD / 128, 512, 0, stream>>>(nf, W1t, b1, sup1);
    spmm1s_k<<<SLICES * SPB, 256, 0, stream>>>(starts, epack, sup1, x16);

    // layer 2 + softmax
    gemm2_k<<<MPAD / 128, 256, 0, stream>>>(x16, W2t, b2, sup2);
    spmm2_sm_k<<<(N_NODES + 3) / 4, 256, 0, stream>>>(starts, epack, sup2, out);

    (void)in_sizes; (void)n_in; (void)out_size; (void)ws_size;
}

// Round 7
// 190.735 us; speedup vs baseline: 1.3368x; 1.3368x over previous
//
#include <hip/hip_runtime.h>

#define N_NODES 50000
#define N_EDGES 800000
#define F_IN    512
#define H_DIM   256
#define C_DIM   64
#define MPAD    50048   // 391 * 128

// sort geometry: bucket = row >> 8 (256 rows/bucket), chunk = 16384 edges
#define NB      196
#define NCHUNK  49
#define CHUNK   16384
#define BCAP    6144

typedef __bf16 bf16;
typedef __bf16 bf16x4 __attribute__((ext_vector_type(4)));
typedef __bf16 bf16x8 __attribute__((ext_vector_type(8)));
typedef float  f32x4  __attribute__((ext_vector_type(4)));
typedef unsigned int u32;
typedef unsigned char u8;

__device__ __forceinline__ void gl_lds16(const void* g, void* l) {
    __builtin_amdgcn_global_load_lds(
        (const __attribute__((address_space(1))) u32*)g,
        (__attribute__((address_space(3))) u32*)l, 16, 0, 0);
}

__device__ __forceinline__ float unpack_val(u32 pk) {
    return __builtin_bit_cast(float, pk << 16);
}

// ---------------- edge sort: two-level counting sort, coalesced writes ----------------

__global__ __launch_bounds__(1024) void histA_k(const int* __restrict__ rows,
                                                u32* __restrict__ G) {
    __shared__ u32 h[16 * NB];
    int tid = threadIdx.x, wid = tid >> 6;
    for (int i = tid; i < 16 * NB; i += 1024) h[i] = 0;
    __syncthreads();
    int base = blockIdx.x * CHUNK;
    int end = base + CHUNK; if (end > N_EDGES) end = N_EDGES;
    for (int e = base + tid; e < end; e += 1024)
        atomicAdd(&h[wid * NB + (rows[e] >> 8)], 1);
    __syncthreads();
    if (tid < NB) {
        u32 s = 0;
#pragma unroll
        for (int w = 0; w < 16; w++) s += h[w * NB + tid];
        G[tid * NCHUNK + blockIdx.x] = s;
    }
}

// scatter: recomputes bucket-base + chunk-prefix locally
__global__ __launch_bounds__(1024) void scatterB_k(const int* __restrict__ rows,
                                                   const int* __restrict__ cols,
                                                   const float* __restrict__ vals,
                                                   const u32* __restrict__ G,
                                                   u32* __restrict__ epack,
                                                   u8* __restrict__ lrow) {
    __shared__ u32 cur[NB];
    __shared__ u32 wtot[16];
    int tid = threadIdx.x, wid = tid >> 6, lane = tid & 63;
    int c = blockIdx.x;
    u32 tot = 0, pre = 0;
    if (tid < NB) {
        for (int cc = 0; cc < NCHUNK; cc++) {
            u32 v = G[tid * NCHUNK + cc];
            tot += v;
            if (cc < c) pre += v;
        }
    }
    u32 incl = tot;
#pragma unroll
    for (int off = 1; off < 64; off <<= 1) {
        u32 u = __shfl_up(incl, off, 64);
        if (lane >= off) incl += u;
    }
    if (lane == 63) wtot[wid] = incl;
    __syncthreads();
    u32 wpre = 0;
#pragma unroll
    for (int w = 0; w < 16; w++)
        if (w < wid) wpre += wtot[w];
    if (tid < NB) cur[tid] = (wpre + incl - tot) + pre;
    __syncthreads();
    int base = c * CHUNK;
    int end = base + CHUNK; if (end > N_EDGES) end = N_EDGES;
    for (int e = base + tid; e < end; e += 1024) {
        int r = rows[e];
        unsigned short vb = __builtin_bit_cast(unsigned short, (bf16)vals[e]);
        u32 pk = ((u32)cols[e] << 16) | (u32)vb;
        u32 p = atomicAdd(&cur[r >> 8], 1);
        epack[p] = pk;
        lrow[p] = (u8)(r & 255);
    }
}

// in-LDS counting sort within bucket; recomputes its bbase locally
__global__ __launch_bounds__(256) void sortC_k(u32* __restrict__ epack,
                                               const u8* __restrict__ lrow,
                                               const u32* __restrict__ G,
                                               int* __restrict__ starts) {
    __shared__ u32 edat[BCAP];
    __shared__ u32 sdat[BCAP];
    __shared__ u8  erow[BCAP];
    __shared__ u32 h[4 * 256];
    __shared__ u32 cur[256];
    __shared__ u32 wt1[4], wt2[4];
    __shared__ u32 sh_s, sh_n;
    int b = blockIdx.x, tid = threadIdx.x, wid = tid >> 6, lane = tid & 63;

    u32 btot = 0;
    if (tid < NB)
        for (int cc = 0; cc < NCHUNK; cc++) btot += G[tid * NCHUNK + cc];
    u32 bincl = btot;
#pragma unroll
    for (int off = 1; off < 64; off <<= 1) {
        u32 u = __shfl_up(bincl, off, 64);
        if (lane >= off) bincl += u;
    }
    if (lane == 63) wt1[wid] = bincl;
    __syncthreads();
    u32 bwpre = 0;
#pragma unroll
    for (int w = 0; w < 4; w++)
        if (w < wid) bwpre += wt1[w];
    if (tid == b) { sh_s = bwpre + bincl - btot; sh_n = btot; }
    __syncthreads();
    int s = (int)sh_s;
    int n = (int)sh_n;
    if (n > BCAP) n = BCAP;

    for (int i = tid; i < n; i += 256) { edat[i] = epack[s + i]; erow[i] = lrow[s + i]; }
    for (int i = tid; i < 1024; i += 256) h[i] = 0;
    __syncthreads();
    for (int i = tid; i < n; i += 256) atomicAdd(&h[wid * 256 + erow[i]], 1);
    __syncthreads();
    u32 tot = h[tid] + h[256 + tid] + h[512 + tid] + h[768 + tid];
    u32 incl = tot;
#pragma unroll
    for (int off = 1; off < 64; off <<= 1) {
        u32 u = __shfl_up(incl, off, 64);
        if (lane >= off) incl += u;
    }
    if (lane == 63) wt2[wid] = incl;
    __syncthreads();
    u32 wpre = 0;
#pragma unroll
    for (int w = 0; w < 4; w++)
        if (w < wid) wpre += wt2[w];
    u32 excl = wpre + incl - tot;
    cur[tid] = excl;
    int grow = b * 256 + tid;
    if (grow < N_NODES) starts[grow] = s + (int)excl;
    if (b == 0 && tid == 0) starts[N_NODES] = N_EDGES;
    __syncthreads();
    for (int i = tid; i < n; i += 256) {
        u32 p = atomicAdd(&cur[erow[i]], 1);
        sdat[p] = edat[i];
    }
    __syncthreads();
    for (int i = tid; i < n; i += 256) epack[s + i] = sdat[i];
}

// ---------------- weight prep (merged) ----------------

__global__ __launch_bounds__(256) void tr_w_k(const float* __restrict__ W1,
                                              const float* __restrict__ W2,
                                              bf16* __restrict__ W1t,
                                              bf16* __restrict__ W2t) {
    int i = blockIdx.x * 256 + threadIdx.x;
    if (i < F_IN * H_DIM) {
        int k = i >> 8, n = i & 255;
        W1t[n * F_IN + k] = (bf16)W1[i];
    } else {
        int j = i - F_IN * H_DIM;
        int k = j >> 6, n = j & 63;
        W2t[n * H_DIM + k] = (bf16)W2[j];
    }
}

// ---------------- GEMM1 fused: C[M,256] = bf16(A_f32[M,512]) @ W1t^T + b1 ----------------

__global__ __launch_bounds__(512) void gemm1_k(const float* __restrict__ A,
                                               const bf16* __restrict__ Bt,
                                               const float* __restrict__ bias,
                                               bf16* __restrict__ C) {
    constexpr int BM = 128, BN = 256, BK = 64;
    __shared__ bf16 As[BM * BK];
    __shared__ bf16 Bs[BN * BK];

    int tid = threadIdx.x;
    int wid = tid >> 6, lane = tid & 63;
    int wr = wid >> 2, wc = wid & 3;
    int bm = blockIdx.x;

    f32x4 acc[4][4];
#pragma unroll
    for (int m = 0; m < 4; m++)
#pragma unroll
        for (int n = 0; n < 4; n++) acc[m][n] = (f32x4){0.f, 0.f, 0.f, 0.f};

    for (int kt = 0; kt < F_IN; kt += BK) {
#pragma unroll
        for (int j = 0; j < 4; j++) {
            int ch = j * 512 + tid;
            int row = ch >> 3, kc = ch & 7;
            gl_lds16(Bt + (size_t)row * F_IN + kt + kc * 8,
                     &Bs[(j * 512 + wid * 64) * 8]);
        }
#pragma unroll
        for (int j = 0; j < 2; j++) {
            int ch = j * 512 + tid;
            int row = ch >> 3, kc = ch & 7;
            int ar = bm * BM + row;
            if (ar >= N_NODES) ar = N_NODES - 1;
            const f32x4* src = (const f32x4*)(A + (size_t)ar * F_IN + kt + kc * 8);
            f32x4 u = src[0], v = src[1];
            bf16x8 o;
            o[0] = (bf16)u[0]; o[1] = (bf16)u[1]; o[2] = (bf16)u[2]; o[3] = (bf16)u[3];
            o[4] = (bf16)v[0]; o[5] = (bf16)v[1]; o[6] = (bf16)v[2]; o[7] = (bf16)v[3];
            *(bf16x8*)&As[(size_t)ch * 8] = o;
        }
        __syncthreads();

        bf16x8 afr[2][4], bfr[2][4];
#pragma unroll
        for (int kk = 0; kk < 2; kk++) {
#pragma unroll
            for (int m = 0; m < 4; m++)
                afr[kk][m] = *(const bf16x8*)&As[(wr * 64 + m * 16 + (lane & 15)) * BK +
                                                 kk * 32 + (lane >> 4) * 8];
#pragma unroll
            for (int n = 0; n < 4; n++)
                bfr[kk][n] = *(const bf16x8*)&Bs[(wc * 64 + n * 16 + (lane & 15)) * BK +
                                                 kk * 32 + (lane >> 4) * 8];
        }
#pragma unroll
        for (int kk = 0; kk < 2; kk++)
#pragma unroll
            for (int m = 0; m < 4; m++)
#pragma unroll
                for (int n = 0; n < 4; n++)
                    acc[m][n] = __builtin_amdgcn_mfma_f32_16x16x32_bf16(
                        afr[kk][m], bfr[kk][n], acc[m][n], 0, 0, 0);
        __syncthreads();
    }

#pragma unroll
    for (int m = 0; m < 4; m++) {
        int row0 = bm * BM + wr * 64 + m * 16 + (lane >> 4) * 4;
#pragma unroll
        for (int n = 0; n < 4; n++) {
            int col = wc * 64 + n * 16 + (lane & 15);
            float bz = bias[col];
#pragma unroll
            for (int r = 0; r < 4; r++) {
                int row = row0 + r;
                if (row < N_NODES)
                    C[(size_t)row * H_DIM + col] = (bf16)(acc[m][n][r] + bz);
            }
        }
    }
}

// ---------------- GEMM2: C[M,64] = x16[M,256] @ W2t^T + b2 (bf16 in/out) ----------------

__global__ __launch_bounds__(256) void gemm2_k(const bf16* __restrict__ A,
                                               const bf16* __restrict__ Bt,
                                               const float* __restrict__ bias,
                                               bf16* __restrict__ C) {
    constexpr int BM = 128, BK = 64;
    __shared__ bf16 As[BM * BK];
    __shared__ bf16 Bs[64 * BK];

    int tid = threadIdx.x;
    int wid = tid >> 6, lane = tid & 63;
    int wr = wid >> 1, wc = wid & 1;
    int bm = blockIdx.x;

    f32x4 acc[4][2];
#pragma unroll
    for (int m = 0; m < 4; m++)
#pragma unroll
        for (int n = 0; n < 2; n++) acc[m][n] = (f32x4){0.f, 0.f, 0.f, 0.f};

    for (int kt = 0; kt < H_DIM; kt += BK) {
#pragma unroll
        for (int j = 0; j < 4; j++) {
            int ch = j * 256 + tid;
            int row = ch >> 3, kc = ch & 7;
            gl_lds16(A + (size_t)(bm * BM + row) * H_DIM + kt + kc * 8,
                     &As[(j * 256 + wid * 64) * 8]);
        }
#pragma unroll
        for (int j = 0; j < 2; j++) {
            int ch = j * 256 + tid;
            int row = ch >> 3, kc = ch & 7;
            gl_lds16(Bt + (size_t)row * H_DIM + kt + kc * 8,
                     &Bs[(j * 256 + wid * 64) * 8]);
        }
        __syncthreads();

        bf16x8 afr[2][4], bfr[2][2];
#pragma unroll
        for (int kk = 0; kk < 2; kk++) {
#pragma unroll
            for (int m = 0; m < 4; m++)
                afr[kk][m] = *(const bf16x8*)&As[(wr * 64 + m * 16 + (lane & 15)) * BK +
                                                 kk * 32 + (lane >> 4) * 8];
#pragma unroll
            for (int n = 0; n < 2; n++)
                bfr[kk][n] = *(const bf16x8*)&Bs[(wc * 32 + n * 16 + (lane & 15)) * BK +
                                                 kk * 32 + (lane >> 4) * 8];
        }
#pragma unroll
        for (int kk = 0; kk < 2; kk++)
#pragma unroll
            for (int m = 0; m < 4; m++)
#pragma unroll
                for (int n = 0; n < 2; n++)
                    acc[m][n] = __builtin_amdgcn_mfma_f32_16x16x32_bf16(
                        afr[kk][m], bfr[kk][n], acc[m][n], 0, 0, 0);
        __syncthreads();
    }

#pragma unroll
    for (int m = 0; m < 4; m++) {
        int row0 = bm * BM + wr * 64 + m * 16 + (lane >> 4) * 4;
#pragma unroll
        for (int n = 0; n < 2; n++) {
            int col = wc * 32 + n * 16 + (lane & 15);
            float bz = bias[col];
#pragma unroll
            for (int r = 0; r < 4; r++) {
                int row = row0 + r;
                if (row < N_NODES)
                    C[(size_t)row * C_DIM + col] = (bf16)(acc[m][n][r] + bz);
            }
        }
    }
}

// ---------------- SpMM1: row-per-wave, 8 gathers in flight, D=256 bf16 ----------------

__global__ __launch_bounds__(256) void spmm1_k(const int* __restrict__ starts,
                                               const u32* __restrict__ epack,
                                               const bf16* __restrict__ s1,
                                               bf16* __restrict__ x16) {
    int wid = threadIdx.x >> 6, lane = threadIdx.x & 63;
    int row = blockIdx.x * 4 + wid;
    if (row >= N_NODES) return;
    int s = starts[row], e = starts[row + 1];
    f32x4 acc = (f32x4){0.f, 0.f, 0.f, 0.f};
    const bf16* s1l = s1 + lane * 4;
    int p = s;
    for (; p + 8 <= e; p += 8) {
        u32 k0 = epack[p],     k1 = epack[p + 1], k2 = epack[p + 2], k3 = epack[p + 3];
        u32 k4 = epack[p + 4], k5 = epack[p + 5], k6 = epack[p + 6], k7 = epack[p + 7];
        bf16x4 g0 = *(const bf16x4*)(s1l + (size_t)(k0 >> 16) * H_DIM);
        bf16x4 g1 = *(const bf16x4*)(s1l + (size_t)(k1 >> 16) * H_DIM);
        bf16x4 g2 = *(const bf16x4*)(s1l + (size_t)(k2 >> 16) * H_DIM);
        bf16x4 g3 = *(const bf16x4*)(s1l + (size_t)(k3 >> 16) * H_DIM);
        bf16x4 g4 = *(const bf16x4*)(s1l + (size_t)(k4 >> 16) * H_DIM);
        bf16x4 g5 = *(const bf16x4*)(s1l + (size_t)(k5 >> 16) * H_DIM);
        bf16x4 g6 = *(const bf16x4*)(s1l + (size_t)(k6 >> 16) * H_DIM);
        bf16x4 g7 = *(const bf16x4*)(s1l + (size_t)(k7 >> 16) * H_DIM);
        float v0 = unpack_val(k0), v1 = unpack_val(k1), v2 = unpack_val(k2), v3 = unpack_val(k3);
        float v4 = unpack_val(k4), v5 = unpack_val(k5), v6 = unpack_val(k6), v7 = unpack_val(k7);
#pragma unroll
        for (int j = 0; j < 4; j++)
            acc[j] += v0 * (float)g0[j] + v1 * (float)g1[j] +
                      v2 * (float)g2[j] + v3 * (float)g3[j] +
                      v4 * (float)g4[j] + v5 * (float)g5[j] +
                      v6 * (float)g6[j] + v7 * (float)g7[j];
    }
    for (; p < e; ++p) {
        u32 k = epack[p];
        float v = unpack_val(k);
        bf16x4 g = *(const bf16x4*)(s1l + (size_t)(k >> 16) * H_DIM);
#pragma unroll
        for (int j = 0; j < 4; j++) acc[j] += v * (float)g[j];
    }
    bf16x4 o;
#pragma unroll
    for (int j = 0; j < 4; j++) o[j] = (bf16)fmaxf(acc[j], 0.f);
    *(bf16x4*)(x16 + (size_t)row * H_DIM + lane * 4) = o;
}

// ---------------- SpMM2 + log_softmax fused: D=64, lane = class, 8-wide ----------------

__global__ __launch_bounds__(256) void spmm2_sm_k(const int* __restrict__ starts,
                                                  const u32* __restrict__ epack,
                                                  const bf16* __restrict__ s2,
                                                  float* __restrict__ out) {
    int wid = threadIdx.x >> 6, lane = threadIdx.x & 63;
    int row = blockIdx.x * 4 + wid;
    if (row >= N_NODES) return;
    int s = starts[row], e = starts[row + 1];
    float acc = 0.f;
    int p = s;
    for (; p + 8 <= e; p += 8) {
        u32 k0 = epack[p],     k1 = epack[p + 1], k2 = epack[p + 2], k3 = epack[p + 3];
        u32 k4 = epack[p + 4], k5 = epack[p + 5], k6 = epack[p + 6], k7 = epack[p + 7];
        float g0 = (float)s2[(size_t)(k0 >> 16) * C_DIM + lane];
        float g1 = (float)s2[(size_t)(k1 >> 16) * C_DIM + lane];
        float g2 = (float)s2[(size_t)(k2 >> 16) * C_DIM + lane];
        float g3 = (float)s2[(size_t)(k3 >> 16) * C_DIM + lane];
        float g4 = (float)s2[(size_t)(k4 >> 16) * C_DIM + lane];
        float g5 = (float)s2[(size_t)(k5 >> 16) * C_DIM + lane];
        float g6 = (float)s2[(size_t)(k6 >> 16) * C_DIM + lane];
        float g7 = (float)s2[(size_t)(k7 >> 16) * C_DIM + lane];
        acc += unpack_val(k0) * g0 + unpack_val(k1) * g1 +
               unpack_val(k2) * g2 + unpack_val(k3) * g3 +
               unpack_val(k4) * g4 + unpack_val(k5) * g5 +
               unpack_val(k6) * g6 + unpack_val(k7) * g7;
    }
    for (; p < e; ++p) {
        u32 k = epack[p];
        acc += unpack_val(k) * (float)s2[(size_t)(k >> 16) * C_DIM + lane];
    }
    float mx = acc;
#pragma unroll
    for (int off = 32; off >= 1; off >>= 1) mx = fmaxf(mx, __shfl_xor(mx, off, 64));
    float ex = expf(acc - mx);
    float se = ex;
#pragma unroll
    for (int off = 32; off >= 1; off >>= 1) se += __shfl_xor(se, off, 64);
    out[(size_t)row * C_DIM + lane] = (acc - mx) - logf(se);
}

// ---------------- launch ----------------

extern "C" void kernel_launch(void* const* d_in, const int* in_sizes, int n_in,
                              void* d_out, int out_size, void* d_ws, size_t ws_size,
                              hipStream_t stream) {
    const float* nf   = (const float*)d_in[0];
    const int*   rows = (const int*)d_in[1];
    const int*   cols = (const int*)d_in[2];
    const float* vals = (const float*)d_in[3];
    const float* W1   = (const float*)d_in[4];
    const float* b1   = (const float*)d_in[5];
    const float* W2   = (const float*)d_in[6];
    const float* b2   = (const float*)d_in[7];
    float* out = (float*)d_out;

    char* w = (char*)d_ws;
    auto alloc = [&](size_t b) { void* p = (void*)w; w += (b + 255) & ~(size_t)255; return p; };

    bf16* x16  = (bf16*)alloc((size_t)MPAD * H_DIM * 2);
    bf16* sup1 = (bf16*)alloc((size_t)N_NODES * H_DIM * 2);
    bf16* sup2 = sup1;   // aliases sup1 (dead by then)
    bf16* W1t = (bf16*)alloc((size_t)H_DIM * F_IN * 2);
    bf16* W2t = (bf16*)alloc((size_t)C_DIM * H_DIM * 2);
    int* starts = (int*)alloc((size_t)(N_NODES + 1) * 4);
    u32* G      = (u32*)alloc((size_t)NB * NCHUNK * 4);
    u32* epack  = (u32*)alloc((size_t)N_EDGES * 4);
    u8*  lrow   = (u8*)alloc((size_t)N_EDGES);

    // edge sort
    histA_k<<<NCHUNK, 1024, 0, stream>>>(rows, G);
    scatterB_k<<<NCHUNK, 1024, 0, stream>>>(rows, cols, vals, G, epack, lrow);
    sortC_k<<<NB, 256, 0, stream>>>(epack, lrow, G, starts);

    // weight prep
    tr_w_k<<<(F_IN * H_DIM + H_DIM * C_DIM) / 256, 256, 0, stream>>>(W1, W2, W1t, W2t);

    // layer 1
    gemm1_k<<<MPAD / 128, 512, 0, stream>>>(nf, W1t, b1, sup1);
    spmm1_k<<<(N_NODES + 3) / 4, 256, 0, stream>>>(starts, epack, sup1, x16);

    // layer 2 + softmax
    gemm2_k<<<MPAD / 128, 256, 0, stream>>>(x16, W2t, b2, sup2);
    spmm2_sm_k<<<(N_NODES + 3) / 4, 256, 0, stream>>>(starts, epack, sup2, out);

    (void)in_sizes; (void)n_in; (void)out_size; (void)ws_size;
}